// Round 2
// baseline (2039.871 us; speedup 1.0000x reference)
//
#include <hip/hip_runtime.h>
#include <cstddef>

#define H_ 256
#define W_ 256
#define HW_ 65536

__device__ __forceinline__ float sigmoidf_(float x) {
    return 1.0f / (1.0f + expf(-x));
}

// ---- transpose OIHW (CO,CI,3,3) -> wT[(ci*9+k)*CO + co] ----
__global__ void transpose_w(const float* __restrict__ src, float* __restrict__ dst,
                            int CO, int CI) {
    int idx = blockIdx.x * blockDim.x + threadIdx.x;
    int n = CO * CI * 9;
    if (idx >= n) return;
    int co = idx / (CI * 9);
    int r  = idx % (CI * 9);
    dst[r * CO + co] = src[idx];
}

// ---- direct 3x3 conv, pad=1. in: (nb,CI,256,256), wT: [(ci*9+k)*CO+co], out: (nb,CO,256,256)
// ACCUM: out += conv (read-modify-write); else out = conv. RELU applied on final value.
template<int CI, int CO, bool RELU, bool ACCUM>
__global__ __launch_bounds__(256) void conv3x3(const float* __restrict__ in,
                                               const float* __restrict__ wT,
                                               float* __restrict__ out) {
    constexpr int TW = 32, TH = 8, CC = 8;
    constexpr int TILE = CC * (TH + 2) * (TW + 2);
    __shared__ float s_in[CC][TH + 2][TW + 2];
    const int tx = threadIdx.x & 31;
    const int ty = threadIdx.x >> 5;
    const int w0 = blockIdx.x * TW;
    const int h0 = blockIdx.y * TH;
    const int b  = blockIdx.z;
    float acc[CO];
#pragma unroll
    for (int i = 0; i < CO; i++) acc[i] = 0.f;

    for (int cb = 0; cb < CI; cb += CC) {
        __syncthreads();
        for (int i = threadIdx.x; i < TILE; i += 256) {
            int ci  = i / ((TH + 2) * (TW + 2));
            int rem = i % ((TH + 2) * (TW + 2));
            int hh  = rem / (TW + 2);
            int ww  = rem % (TW + 2);
            int h = h0 - 1 + hh, w = w0 - 1 + ww;
            float v = 0.f;
            if (h >= 0 && h < H_ && w >= 0 && w < W_)
                v = in[(((size_t)b * CI + cb + ci) * H_ + h) * W_ + w];
            s_in[ci][hh][ww] = v;
        }
        __syncthreads();
        for (int ci = 0; ci < CC; ci++) {
            float nb9[9];
#pragma unroll
            for (int kh = 0; kh < 3; kh++)
#pragma unroll
                for (int kw = 0; kw < 3; kw++)
                    nb9[kh * 3 + kw] = s_in[ci][ty + kh][tx + kw];
            const float* wp = wT + (size_t)(cb + ci) * 9 * CO;
#pragma unroll
            for (int k = 0; k < 9; k++) {
#pragma unroll
                for (int co = 0; co < CO; co++)
                    acc[co] = fmaf(nb9[k], wp[k * CO + co], acc[co]);
            }
        }
    }
    size_t obase = (((size_t)b * CO) * H_ + (h0 + ty)) * W_ + (w0 + tx);
#pragma unroll
    for (int co = 0; co < CO; co++) {
        size_t oi = obase + (size_t)co * (size_t)HW_;
        float v = acc[co];
        if (ACCUM) v += out[oi];
        if (RELU) v = fmaxf(v, 0.f);
        out[oi] = v;
    }
}

// ---- attention head: 1x1 conv (16->4) + bias + sigmoid. grid = nb*256 blocks ----
__global__ __launch_bounds__(256) void att1x1(const float* __restrict__ a2,
                                              const float* __restrict__ w,
                                              const float* __restrict__ bias,
                                              float* __restrict__ wmap) {
    int idx = blockIdx.x * 256 + threadIdx.x;  // nb*H*W
    int b = idx >> 16;
    int p = idx & 65535;
    float acc0 = bias[0], acc1 = bias[1], acc2 = bias[2], acc3 = bias[3];
#pragma unroll
    for (int ci = 0; ci < 16; ci++) {
        float v = a2[((size_t)b * 16 + ci) * HW_ + p];
        acc0 = fmaf(v, w[0 * 16 + ci], acc0);
        acc1 = fmaf(v, w[1 * 16 + ci], acc1);
        acc2 = fmaf(v, w[2 * 16 + ci], acc2);
        acc3 = fmaf(v, w[3 * 16 + ci], acc3);
    }
    size_t ob = (size_t)b * 4 * HW_ + p;
    wmap[ob]             = sigmoidf_(acc0);
    wmap[ob + HW_]       = sigmoidf_(acc1);
    wmap[ob + 2 * HW_]   = sigmoidf_(acc2);
    wmap[ob + 3 * HW_]   = sigmoidf_(acc3);
}

// ---- final: relu on load (deferred from conv w3), 1x1 conv (32->1) + sigmoid ----
__global__ __launch_bounds__(256) void out1x1(const float* __restrict__ feat,
                                              const float* __restrict__ w,
                                              float* __restrict__ out) {
    int idx = blockIdx.x * 256 + threadIdx.x;
    int b = idx >> 16;
    int p = idx & 65535;
    float acc = 0.f;
#pragma unroll
    for (int ci = 0; ci < 32; ci++) {
        float v = fmaxf(feat[((size_t)b * 32 + ci) * HW_ + p], 0.f);
        acc = fmaf(v, w[ci], acc);
    }
    out[idx] = sigmoidf_(acc);
}

// ---- vertical IRNN scan (axis=H) + gating by wmap channel `group`.
// out gdir: (nb,32,H,W). grid = nb*32 blocks of 256 threads (one per column).
template<int FWD>
__global__ __launch_bounds__(256) void vscan(const float* __restrict__ feat,
                                             const float* __restrict__ alpha,
                                             const float* __restrict__ wmap,
                                             float* __restrict__ gdir, int group) {
    int b = blockIdx.x >> 5;
    int c = blockIdx.x & 31;
    int w = threadIdx.x;
    float a = alpha[c];
    const float* ip = feat + (((size_t)b * 32 + c) * H_) * W_ + w;
    const float* wp = wmap + (((size_t)b * 4 + group) * H_) * W_ + w;
    float* op = gdir + (((size_t)b * 32 + c) * H_) * W_ + w;
    float prev = 0.f;
    for (int i = 0; i < H_; i++) {
        int h = FWD ? i : (H_ - 1 - i);
        float v = ip[h * W_];
        float cur = fmaxf(v + a * prev, 0.f);
        prev = cur;
        op[h * W_] = cur * wp[h * W_];
    }
}

// ---- horizontal IRNN scan (axis=W) + gating. grid = nb*32 blocks, thread per row.
template<int FWD>
__global__ __launch_bounds__(256) void hscan(const float* __restrict__ feat,
                                             const float* __restrict__ alpha,
                                             const float* __restrict__ wmap,
                                             float* __restrict__ gdir, int group) {
    int b = blockIdx.x >> 5;
    int c = blockIdx.x & 31;
    int h = threadIdx.x;
    float a = alpha[c];
    const float4* in4 = (const float4*)(feat + ((((size_t)b * 32 + c) * H_) + h) * W_);
    const float4* w4  = (const float4*)(wmap + ((((size_t)b * 4 + group) * H_) + h) * W_);
    float4* o4 = (float4*)(gdir + ((((size_t)b * 32 + c) * H_) + h) * W_);
    float prev = 0.f;
    if (FWD) {
        for (int ch = 0; ch < W_ / 4; ch++) {
            float4 v = in4[ch];
            float4 wm = w4[ch];
            float c0 = fmaxf(v.x + a * prev, 0.f);
            float c1 = fmaxf(v.y + a * c0, 0.f);
            float c2 = fmaxf(v.z + a * c1, 0.f);
            float c3 = fmaxf(v.w + a * c2, 0.f);
            prev = c3;
            float4 o; o.x = c0 * wm.x; o.y = c1 * wm.y; o.z = c2 * wm.z; o.w = c3 * wm.w;
            o4[ch] = o;
        }
    } else {
        for (int ch = W_ / 4 - 1; ch >= 0; ch--) {
            float4 v = in4[ch];
            float4 wm = w4[ch];
            float c3 = fmaxf(v.w + a * prev, 0.f);
            float c2 = fmaxf(v.z + a * c3, 0.f);
            float c1 = fmaxf(v.y + a * c2, 0.f);
            float c0 = fmaxf(v.x + a * c1, 0.f);
            prev = c0;
            float4 o; o.x = c0 * wm.x; o.y = c1 * wm.y; o.z = c2 * wm.z; o.w = c3 * wm.w;
            o4[ch] = o;
        }
    }
}

// Run the whole pipeline for `nb` batch images starting at x (and out).
static void run_pipeline(const float* x, int nb,
                         const float* alpha1, const float* alpha2,
                         const float* aw3, const float* ab3, const float* wout,
                         const float* wInT, const float* w2T, const float* w3T,
                         const float* aw1T, const float* aw2T,
                         float* feat, float* acc, float* gdir, float* wmap,
                         float* out, hipStream_t stream) {
    dim3 blk(256);
    dim3 gconv(W_ / 32, H_ / 8, nb);

    // attention gate: a1/a2 overlay gdir (dead until scans start)
    float* a1 = gdir;
    float* a2 = gdir + (size_t)nb * 16 * HW_;
    conv3x3<32, 16, true,  false><<<gconv, blk, 0, stream>>>(x, aw1T, a1);
    conv3x3<16, 16, true,  false><<<gconv, blk, 0, stream>>>(a1, aw2T, a2);
    att1x1<<<nb * 256, 256, 0, stream>>>(a2, aw3, ab3, wmap);

    // trunk
    conv3x3<32, 32, false, false><<<gconv, blk, 0, stream>>>(x, wInT, feat);

    // round 1: scan dir g -> gdir, conv with w2 slice g, accumulate into acc
    vscan<1><<<nb * 32, 256, 0, stream>>>(feat, alpha1, wmap, gdir, 0);
    conv3x3<32, 32, false, false><<<gconv, blk, 0, stream>>>(gdir, w2T + (size_t)0 * 32 * 9 * 32, acc);
    hscan<1><<<nb * 32, 256, 0, stream>>>(feat, alpha1, wmap, gdir, 1);
    conv3x3<32, 32, false, true ><<<gconv, blk, 0, stream>>>(gdir, w2T + (size_t)1 * 32 * 9 * 32, acc);
    vscan<0><<<nb * 32, 256, 0, stream>>>(feat, alpha1, wmap, gdir, 2);
    conv3x3<32, 32, false, true ><<<gconv, blk, 0, stream>>>(gdir, w2T + (size_t)2 * 32 * 9 * 32, acc);
    hscan<0><<<nb * 32, 256, 0, stream>>>(feat, alpha1, wmap, gdir, 3);
    conv3x3<32, 32, false, true ><<<gconv, blk, 0, stream>>>(gdir, w2T + (size_t)3 * 32 * 9 * 32, acc);

    // round 2: scans read acc; conv w3 accumulates into feat (old feat dead).
    // relu of conv w3 deferred to out1x1's load.
    vscan<1><<<nb * 32, 256, 0, stream>>>(acc, alpha2, wmap, gdir, 0);
    conv3x3<32, 32, false, false><<<gconv, blk, 0, stream>>>(gdir, w3T + (size_t)0 * 32 * 9 * 32, feat);
    hscan<1><<<nb * 32, 256, 0, stream>>>(acc, alpha2, wmap, gdir, 1);
    conv3x3<32, 32, false, true ><<<gconv, blk, 0, stream>>>(gdir, w3T + (size_t)1 * 32 * 9 * 32, feat);
    vscan<0><<<nb * 32, 256, 0, stream>>>(acc, alpha2, wmap, gdir, 2);
    conv3x3<32, 32, false, true ><<<gconv, blk, 0, stream>>>(gdir, w3T + (size_t)2 * 32 * 9 * 32, feat);
    hscan<0><<<nb * 32, 256, 0, stream>>>(acc, alpha2, wmap, gdir, 3);
    conv3x3<32, 32, false, true ><<<gconv, blk, 0, stream>>>(gdir, w3T + (size_t)3 * 32 * 9 * 32, feat);

    out1x1<<<nb * 256, 256, 0, stream>>>(feat, wout, out);
}

extern "C" void kernel_launch(void* const* d_in, const int* in_sizes, int n_in,
                              void* d_out, int out_size, void* d_ws, size_t ws_size,
                              hipStream_t stream) {
    const float* x      = (const float*)d_in[0];
    const float* alpha1 = (const float*)d_in[1];
    const float* alpha2 = (const float*)d_in[2];
    const float* w_in   = (const float*)d_in[3];
    const float* w2     = (const float*)d_in[4];
    const float* w3     = (const float*)d_in[5];
    const float* aw1    = (const float*)d_in[6];
    const float* aw2    = (const float*)d_in[7];
    const float* aw3    = (const float*)d_in[8];
    const float* ab3    = (const float*)d_in[9];
    const float* wout   = (const float*)d_in[10];
    float* out = (float*)d_out;

    // ---- arena carve (floats) ----
    float* p = (float*)d_ws;
    float* wInT = p; p += 32 * 32 * 9;    // 9216
    float* w2T  = p; p += 128 * 32 * 9;   // 36864
    float* w3T  = p; p += 128 * 32 * 9;   // 36864
    float* aw1T = p; p += 32 * 16 * 9;    // 4608
    float* aw2T = p; p += 16 * 16 * 9;    // 2304
    const size_t wfloats = 9216 + 36864 + 36864 + 4608 + 2304;

    // weight transposes (once, shared by both paths)
    transpose_w<<<(32 * 32 * 9 + 255) / 256, 256, 0, stream>>>(w_in, wInT, 32, 32);
    transpose_w<<<(32 * 128 * 9 + 255) / 256, 256, 0, stream>>>(w2, w2T, 32, 128);
    transpose_w<<<(32 * 128 * 9 + 255) / 256, 256, 0, stream>>>(w3, w3T, 32, 128);
    transpose_w<<<(16 * 32 * 9 + 255) / 256, 256, 0, stream>>>(aw1, aw1T, 16, 32);
    transpose_w<<<(16 * 16 * 9 + 255) / 256, 256, 0, stream>>>(aw2, aw2T, 16, 16);

    const size_t avail = ws_size / sizeof(float) - wfloats;
    // per-image needs: feat 32*HW + acc 32*HW + gdir 32*HW + wmap 4*HW = 100*HW floats
    const size_t need_full = (size_t)8 * HW_ * 100;   // 52,428,800 floats ≈ 210 MB
    const int nb = (avail >= need_full) ? 8 : 1;

    float* feat = p; p += (size_t)nb * 32 * HW_;
    float* acc  = p; p += (size_t)nb * 32 * HW_;
    float* gdir = p; p += (size_t)nb * 32 * HW_;
    float* wmap = p; p += (size_t)nb * 4 * HW_;

    if (nb == 8) {
        run_pipeline(x, 8, alpha1, alpha2, aw3, ab3, wout,
                     wInT, w2T, w3T, aw1T, aw2T,
                     feat, acc, gdir, wmap, out, stream);
    } else {
        for (int b = 0; b < 8; b++) {
            run_pipeline(x + (size_t)b * 32 * HW_, 1, alpha1, alpha2, aw3, ab3, wout,
                         wInT, w2T, w3T, aw1T, aw2T,
                         feat, acc, gdir, wmap, out + (size_t)b * HW_, stream);
        }
    }
}

// Round 3
// 483.614 us; speedup vs baseline: 4.2180x; 4.2180x over previous
//
#include <hip/hip_runtime.h>
#include <cstddef>

#define H_ 256
#define W_ 256
#define HW_ 65536

typedef unsigned int uint;
typedef unsigned short ushort;
typedef __attribute__((ext_vector_type(8))) short short8;
typedef __attribute__((ext_vector_type(16))) float floatx16;

__device__ __forceinline__ float bf2f(ushort u) {
    return __uint_as_float(((uint)u) << 16);
}
__device__ __forceinline__ ushort f2bf(float f) {
    uint u = __float_as_uint(f);
    uint r = (u + 0x7fffu + ((u >> 16) & 1u)) >> 16;
    return (ushort)r;
}
__device__ __forceinline__ float sigmoidf_(float x) {
    return 1.0f / (1.0f + expf(-x));
}

// ============ weight prep: OIHW fp32 -> MFMA-fragment-ordered bf16 ============
// dst layout: for element (chunk, co, kk) with kk = khw*32+ci:
//   s = kk>>4, lane = ((kk>>3)&1)*32 + co, j = kk&7
//   dst[((chunk*18 + s)*64 + lane)*8 + j]
__device__ __forceinline__ void prep_one(const float* src, ushort* dst,
                                         int CO, int CI, int e) {
    int chunk = e / 9216;
    int r = e - chunk * 9216;
    int co = r / 288;
    int kk = r - co * 288;
    int khw = kk >> 5;
    int ci = kk & 31;
    int cig = chunk * 32 + ci;
    float v = 0.f;
    if (co < CO && cig < CI) v = src[(co * CI + cig) * 9 + khw];
    int s = kk >> 4;
    int lane = ((kk >> 3) & 1) * 32 + co;
    int j = kk & 7;
    dst[(((size_t)chunk * 18 + s) * 64 + lane) * 8 + j] = f2bf(v);
}

__global__ __launch_bounds__(256) void prep_weights(
    const float* __restrict__ w_in, const float* __restrict__ w2,
    const float* __restrict__ w3, const float* __restrict__ aw1,
    const float* __restrict__ aw2,
    ushort* __restrict__ w_inB, ushort* __restrict__ w2B,
    ushort* __restrict__ w3B, ushort* __restrict__ aw1B,
    ushort* __restrict__ aw2B) {
    int idx = blockIdx.x * 256 + threadIdx.x;
    if (idx < 9216)        prep_one(w_in, w_inB, 32, 32, idx);
    else if (idx < 46080)  prep_one(w2, w2B, 32, 128, idx - 9216);
    else if (idx < 82944)  prep_one(w3, w3B, 32, 128, idx - 46080);
    else if (idx < 92160)  prep_one(aw1, aw1B, 16, 32, idx - 82944);
    else if (idx < 101376) prep_one(aw2, aw2B, 16, 16, idx - 92160);
}

// ============ x: NCHW fp32 -> NHWC bf16 (32 ch) ============
__global__ __launch_bounds__(256) void transform_x(const float* __restrict__ x,
                                                   ushort* __restrict__ xh) {
    __shared__ float s[64][33];
    const int t = threadIdx.x;
    const int w0 = blockIdx.x * 64, h = blockIdx.y, b = blockIdx.z;
    {
        int ww = t & 63, c0 = (t >> 6) * 8;
#pragma unroll
        for (int j = 0; j < 8; j++) {
            int c = c0 + j;
            s[ww][c] = x[((size_t)(b * 32 + c)) * HW_ + h * W_ + w0 + ww];
        }
    }
    __syncthreads();
    {
        int p = t >> 2, cb = t & 3;
        ushort tmp[8];
#pragma unroll
        for (int j = 0; j < 8; j++) tmp[j] = f2bf(s[p][cb * 8 + j]);
        *(uint4*)(xh + (((size_t)b * HW_ + h * W_ + w0 + p) * 32) + cb * 8) =
            *(const uint4*)tmp;
    }
}

// ============ implicit-GEMM conv 3x3 pad=1, NHWC bf16, MFMA 32x32x16 ============
// in: NCHUNK tensors (nb,H,W,32) bf16. wB fragment-ordered. out NHWC bf16 32ch.
template<int NCHUNK, int COOUT, bool RELU>
__global__ __launch_bounds__(256) void conv_mfma(
    const ushort* __restrict__ in0, const ushort* __restrict__ in1,
    const ushort* __restrict__ in2, const ushort* __restrict__ in3,
    const ushort* __restrict__ wB, ushort* __restrict__ outp) {
    __shared__ __align__(16) ushort smem[10880];  // 10 rows x 34 px x 4 blk x 8 bf16
    const int t = threadIdx.x;
    const int wid = t >> 6;
    const int lane = t & 63;
    const int lco = lane & 31, lhalf = lane >> 5;
    const int w0 = blockIdx.x * 32, h0 = blockIdx.y * 8, b = blockIdx.z;
    const ushort* ins[4] = {in0, in1, in2, in3};

    floatx16 acc0, acc1;
#pragma unroll
    for (int i = 0; i < 16; i++) { acc0[i] = 0.f; acc1[i] = 0.f; }

#pragma unroll
    for (int ch = 0; ch < NCHUNK; ch++) {
        // B fragment preload (fragment-ordered: contiguous 1KB per step)
        short8 bfrag[18];
        const ushort* wbp = wB + (((size_t)ch * 18) * 64 + lane) * 8;
#pragma unroll
        for (int s = 0; s < 18; s++)
            bfrag[s] = *(const short8*)(wbp + (size_t)s * 64 * 8);

        __syncthreads();  // protect smem from previous chunk's readers
        const ushort* inp = ins[ch];
        for (int u = t; u < 1360; u += 256) {
            int row = u / 136, rem = u - row * 136;
            int p = rem >> 2, cb = rem & 3;
            int gh = h0 - 1 + row, gw = w0 - 1 + p;
            uint4 v = make_uint4(0, 0, 0, 0);
            if ((unsigned)gh < 256u && (unsigned)gw < 256u)
                v = *(const uint4*)(inp + (((size_t)b * HW_ + gh * W_ + gw) * 32) + cb * 8);
            int slot = cb ^ (p & 3) ^ ((p >> 2) & 3);
            *(uint4*)(smem + ((size_t)(row * 34 + p) * 4 + slot) * 8) = v;
        }
        __syncthreads();

#pragma unroll
        for (int s = 0; s < 18; s++) {
            const int khw = s >> 1;
            const int kh = khw / 3, kw = khw - kh * 3;
            const int cbr = ((s & 1) << 1) + lhalf;
            const int ww = (lane & 31) + kw;
            const int slot = cbr ^ (ww & 3) ^ ((ww >> 2) & 3);
            const int base = ((wid * 2 + kh) * 34 + ww) * 4;
            short8 a0 = *(const short8*)(smem + (size_t)(base + slot) * 8);
            short8 a1 = *(const short8*)(smem + (size_t)(base + 136 + slot) * 8);
            acc0 = __builtin_amdgcn_mfma_f32_32x32x16_bf16(a0, bfrag[s], acc0, 0, 0, 0);
            acc1 = __builtin_amdgcn_mfma_f32_32x32x16_bf16(a1, bfrag[s], acc1, 0, 0, 0);
        }
    }

    // epilogue: D col = co = lane&31; row(pixel) = (r&3) + 8*(r>>2) + 4*half
#pragma unroll
    for (int r = 0; r < 16; r++) {
        int prow = (r & 3) + 8 * (r >> 2) + 4 * lhalf;
        float v0 = acc0[r], v1 = acc1[r];
        if (RELU) { v0 = fmaxf(v0, 0.f); v1 = fmaxf(v1, 0.f); }
        ushort u0 = (lco < COOUT) ? f2bf(v0) : (ushort)0;
        ushort u1 = (lco < COOUT) ? f2bf(v1) : (ushort)0;
        size_t p0 = (((size_t)b * HW_ + (h0 + wid * 2) * W_ + w0 + prow) * 32) + lco;
        outp[p0] = u0;
        outp[p0 + (size_t)W_ * 32] = u1;
    }
}

// ============ attention head: 1x1 conv (16->4) + bias + sigmoid ============
__global__ __launch_bounds__(256) void att1x1(const ushort* __restrict__ a2,
                                              const float* __restrict__ w,
                                              const float* __restrict__ bias,
                                              ushort* __restrict__ wmap) {
    int idx = blockIdx.x * 256 + threadIdx.x;  // 8*HW
    float xin[16];
    {
        uint4 v0 = *(const uint4*)(a2 + (size_t)idx * 32);
        uint4 v1 = *(const uint4*)(a2 + (size_t)idx * 32 + 8);
        const ushort* u = (const ushort*)&v0;
#pragma unroll
        for (int j = 0; j < 8; j++) xin[j] = bf2f(u[j]);
        const ushort* u2 = (const ushort*)&v1;
#pragma unroll
        for (int j = 0; j < 8; j++) xin[8 + j] = bf2f(u2[j]);
    }
    ushort o[4];
#pragma unroll
    for (int g = 0; g < 4; g++) {
        float acc = bias[g];
#pragma unroll
        for (int ci = 0; ci < 16; ci++) acc = fmaf(xin[ci], w[g * 16 + ci], acc);
        o[g] = f2bf(sigmoidf_(acc));
    }
    *(uint2*)(wmap + (size_t)idx * 4) = *(const uint2*)o;
}

// ============ final 1x1 conv (32->1) + sigmoid, fp32 out ============
__global__ __launch_bounds__(256) void out1x1(const ushort* __restrict__ feat,
                                              const float* __restrict__ w,
                                              float* __restrict__ out) {
    int idx = blockIdx.x * 256 + threadIdx.x;
    float acc = 0.f;
    const ushort* f = feat + (size_t)idx * 32;
#pragma unroll
    for (int q = 0; q < 4; q++) {
        uint4 v = *(const uint4*)(f + q * 8);
        const ushort* u = (const ushort*)&v;
#pragma unroll
        for (int j = 0; j < 8; j++) acc = fmaf(bf2f(u[j]), w[q * 8 + j], acc);
    }
    out[idx] = sigmoidf_(acc);
}

// ============ vertical IRNN scan (axis=H) + gating, NHWC bf16 ============
template<int FWD>
__global__ __launch_bounds__(256) void vscan(const ushort* __restrict__ feat,
                                             const float* __restrict__ alpha,
                                             const ushort* __restrict__ wmap,
                                             ushort* __restrict__ gdir, int group) {
    int tid = blockIdx.x * 256 + threadIdx.x;  // b*8192 + w*32 + c
    int c = tid & 31;
    int w = (tid >> 5) & 255;
    int b = tid >> 13;
    float a = alpha[c];
    const ushort* ip = feat + ((size_t)b * HW_ + w) * 32 + c;   // h stride 8192
    const ushort* wp = wmap + ((size_t)b * HW_ + w) * 4 + group; // h stride 1024
    ushort* op = gdir + ((size_t)b * HW_ + w) * 32 + c;

    ushort xa[8], wa[8], xb[8], wb[8];
    auto loadg = [&](int g, ushort* xd, ushort* wd) {
#pragma unroll
        for (int j = 0; j < 8; j++) {
            int h = g * 8 + j;
            int hh = FWD ? h : 255 - h;
            xd[j] = ip[(size_t)hh * 8192];
            wd[j] = wp[(size_t)hh * 1024];
        }
    };
    float prev = 0.f;
    auto computeg = [&](int g, const ushort* xd, const ushort* wd) {
#pragma unroll
        for (int j = 0; j < 8; j++) {
            int h = g * 8 + j;
            int hh = FWD ? h : 255 - h;
            float cur = fmaxf(fmaf(a, prev, bf2f(xd[j])), 0.f);
            prev = cur;
            op[(size_t)hh * 8192] = f2bf(cur * bf2f(wd[j]));
        }
    };
    loadg(0, xa, wa);
    for (int g = 0; g < 32; g += 2) {
        if (g + 1 < 32) loadg(g + 1, xb, wb);
        computeg(g, xa, wa);
        if (g + 2 < 32) loadg(g + 2, xa, wa);
        if (g + 1 < 32) computeg(g + 1, xb, wb);
    }
}

// ============ horizontal IRNN scan (axis=W) + gating, NHWC bf16 ============
template<int FWD>
__global__ __launch_bounds__(256) void hscan(const ushort* __restrict__ feat,
                                             const float* __restrict__ alpha,
                                             const ushort* __restrict__ wmap,
                                             ushort* __restrict__ gdir, int group) {
    int tid = blockIdx.x * 256 + threadIdx.x;  // b*8192 + h*32 + c
    int c = tid & 31;
    int h = (tid >> 5) & 255;
    int b = tid >> 13;
    float a = alpha[c];
    const ushort* ip = feat + ((size_t)b * HW_ + (size_t)h * W_) * 32 + c;  // w stride 32
    const ushort* wp = wmap + ((size_t)b * HW_ + (size_t)h * W_) * 4 + group; // w stride 4
    ushort* op = gdir + ((size_t)b * HW_ + (size_t)h * W_) * 32 + c;

    ushort xa[8], wa[8], xb[8], wb[8];
    auto loadg = [&](int g, ushort* xd, ushort* wd) {
#pragma unroll
        for (int j = 0; j < 8; j++) {
            int w = g * 8 + j;
            int ww = FWD ? w : 255 - w;
            xd[j] = ip[(size_t)ww * 32];
            wd[j] = wp[(size_t)ww * 4];
        }
    };
    float prev = 0.f;
    auto computeg = [&](int g, const ushort* xd, const ushort* wd) {
#pragma unroll
        for (int j = 0; j < 8; j++) {
            int w = g * 8 + j;
            int ww = FWD ? w : 255 - w;
            float cur = fmaxf(fmaf(a, prev, bf2f(xd[j])), 0.f);
            prev = cur;
            op[(size_t)ww * 32] = f2bf(cur * bf2f(wd[j]));
        }
    };
    loadg(0, xa, wa);
    for (int g = 0; g < 32; g += 2) {
        if (g + 1 < 32) loadg(g + 1, xb, wb);
        computeg(g, xa, wa);
        if (g + 2 < 32) loadg(g + 2, xa, wa);
        if (g + 1 < 32) computeg(g + 1, xb, wb);
    }
}

extern "C" void kernel_launch(void* const* d_in, const int* in_sizes, int n_in,
                              void* d_out, int out_size, void* d_ws, size_t ws_size,
                              hipStream_t stream) {
    const float* x      = (const float*)d_in[0];
    const float* alpha1 = (const float*)d_in[1];
    const float* alpha2 = (const float*)d_in[2];
    const float* w_in   = (const float*)d_in[3];
    const float* w2     = (const float*)d_in[4];
    const float* w3     = (const float*)d_in[5];
    const float* aw1    = (const float*)d_in[6];
    const float* aw2    = (const float*)d_in[7];
    const float* aw3    = (const float*)d_in[8];
    const float* ab3    = (const float*)d_in[9];
    const float* wout   = (const float*)d_in[10];
    float* out = (float*)d_out;

    // ---- workspace carve (ushorts). total ~205.8 MB ----
    const size_t TEN = (size_t)8 * HW_ * 32;  // 16,777,216 elements per 32-ch tensor
    ushort* p = (ushort*)d_ws;
    ushort* xh    = p; p += TEN;
    ushort* feat  = p; p += TEN;
    ushort* g0    = p; p += TEN;
    ushort* g1    = p; p += TEN;
    ushort* g2    = p; p += TEN;
    ushort* g3    = p; p += TEN;
    ushort* wmap  = p; p += (size_t)8 * HW_ * 4;
    ushort* w_inB = p; p += 9216;
    ushort* w2B   = p; p += 36864;
    ushort* w3B   = p; p += 36864;
    ushort* aw1B  = p; p += 9216;
    ushort* aw2B  = p; p += 9216;

    prep_weights<<<396, 256, 0, stream>>>(w_in, w2, w3, aw1, aw2,
                                          w_inB, w2B, w3B, aw1B, aw2B);
    transform_x<<<dim3(4, 256, 8), 256, 0, stream>>>(x, xh);

    dim3 gconv(8, 32, 8);
    // attention gate (a1/a2 overlay g0/g1; both written zero-padded to 32ch)
    conv_mfma<1, 16, true><<<gconv, 256, 0, stream>>>(xh, xh, xh, xh, aw1B, g0);
    conv_mfma<1, 16, true><<<gconv, 256, 0, stream>>>(g0, g0, g0, g0, aw2B, g1);
    att1x1<<<2048, 256, 0, stream>>>(g1, aw3, ab3, wmap);

    // trunk
    conv_mfma<1, 32, false><<<gconv, 256, 0, stream>>>(xh, xh, xh, xh, w_inB, feat);

    // round 1 scans (gating fused): 0=td, 1=lr, 2=dt, 3=rl
    vscan<1><<<256, 256, 0, stream>>>(feat, alpha1, wmap, g0, 0);
    hscan<1><<<256, 256, 0, stream>>>(feat, alpha1, wmap, g1, 1);
    vscan<0><<<256, 256, 0, stream>>>(feat, alpha1, wmap, g2, 2);
    hscan<0><<<256, 256, 0, stream>>>(feat, alpha1, wmap, g3, 3);

    conv_mfma<4, 32, false><<<gconv, 256, 0, stream>>>(g0, g1, g2, g3, w2B, feat);

    // round 2 scans
    vscan<1><<<256, 256, 0, stream>>>(feat, alpha2, wmap, g0, 0);
    hscan<1><<<256, 256, 0, stream>>>(feat, alpha2, wmap, g1, 1);
    vscan<0><<<256, 256, 0, stream>>>(feat, alpha2, wmap, g2, 2);
    hscan<0><<<256, 256, 0, stream>>>(feat, alpha2, wmap, g3, 3);

    conv_mfma<4, 32, true><<<gconv, 256, 0, stream>>>(g0, g1, g2, g3, w3B, feat);

    out1x1<<<2048, 256, 0, stream>>>(feat, wout, out);
}

// Round 4
// 474.899 us; speedup vs baseline: 4.2954x; 1.0184x over previous
//
#include <hip/hip_runtime.h>
#include <cstddef>

#define H_ 256
#define W_ 256
#define HW_ 65536

typedef unsigned int uint;
typedef unsigned short ushort;
typedef __attribute__((ext_vector_type(8))) short short8;
typedef __attribute__((ext_vector_type(16))) float floatx16;

__device__ __forceinline__ float bf2f(ushort u) {
    return __uint_as_float(((uint)u) << 16);
}
__device__ __forceinline__ ushort f2bf(float f) {
    uint u = __float_as_uint(f);
    uint r = (u + 0x7fffu + ((u >> 16) & 1u)) >> 16;
    return (ushort)r;
}
__device__ __forceinline__ float sigmoidf_(float x) {
    return 1.0f / (1.0f + expf(-x));
}

// ============ weight prep: OIHW fp32 -> MFMA-fragment-ordered bf16 ============
__device__ __forceinline__ void prep_one(const float* src, ushort* dst,
                                         int CO, int CI, int e) {
    int chunk = e / 9216;
    int r = e - chunk * 9216;
    int co = r / 288;
    int kk = r - co * 288;
    int khw = kk >> 5;
    int ci = kk & 31;
    int cig = chunk * 32 + ci;
    float v = 0.f;
    if (co < CO && cig < CI) v = src[(co * CI + cig) * 9 + khw];
    int s = kk >> 4;
    int lane = ((kk >> 3) & 1) * 32 + co;
    int j = kk & 7;
    dst[(((size_t)chunk * 18 + s) * 64 + lane) * 8 + j] = f2bf(v);
}

__global__ __launch_bounds__(256) void prep_weights(
    const float* __restrict__ w_in, const float* __restrict__ w2,
    const float* __restrict__ w3, const float* __restrict__ aw1,
    const float* __restrict__ aw2,
    ushort* __restrict__ w_inB, ushort* __restrict__ w2B,
    ushort* __restrict__ w3B, ushort* __restrict__ aw1B,
    ushort* __restrict__ aw2B, ushort* __restrict__ zp) {
    int idx = blockIdx.x * 256 + threadIdx.x;
    if (idx < 64) zp[idx] = 0;
    if (idx < 9216)        prep_one(w_in, w_inB, 32, 32, idx);
    else if (idx < 46080)  prep_one(w2, w2B, 32, 128, idx - 9216);
    else if (idx < 82944)  prep_one(w3, w3B, 32, 128, idx - 46080);
    else if (idx < 92160)  prep_one(aw1, aw1B, 16, 32, idx - 82944);
    else if (idx < 101376) prep_one(aw2, aw2B, 16, 16, idx - 92160);
}

// ============ x: NCHW fp32 -> NHWC bf16 (32 ch) ============
__global__ __launch_bounds__(256) void transform_x(const float* __restrict__ x,
                                                   ushort* __restrict__ xh) {
    __shared__ float s[64][33];
    const int t = threadIdx.x;
    const int w0 = blockIdx.x * 64, h = blockIdx.y, b = blockIdx.z;
    {
        int ww = t & 63, c0 = (t >> 6) * 8;
#pragma unroll
        for (int j = 0; j < 8; j++) {
            int c = c0 + j;
            s[ww][c] = x[((size_t)(b * 32 + c)) * HW_ + h * W_ + w0 + ww];
        }
    }
    __syncthreads();
    {
        int p = t >> 2, cb = t & 3;
        ushort tmp[8];
#pragma unroll
        for (int j = 0; j < 8; j++) tmp[j] = f2bf(s[p][cb * 8 + j]);
        *(uint4*)(xh + (((size_t)b * HW_ + h * W_ + w0 + p) * 32) + cb * 8) =
            *(const uint4*)tmp;
    }
}

// ============ implicit-GEMM conv 3x3 pad=1, NHWC bf16, MFMA 32x32x16 ============
// Double-buffered LDS staging via global_load_lds; layout [row(10)][cb(4)][p(34)],
// each slot = 16B (8 channels of one pixel). OOB lanes read a zero page.
template<int NCHUNK, int COOUT, bool RELU>
__global__ __launch_bounds__(256) void conv_mfma(
    const ushort* __restrict__ in0, const ushort* __restrict__ in1,
    const ushort* __restrict__ in2, const ushort* __restrict__ in3,
    const ushort* __restrict__ wB, const ushort* __restrict__ zp,
    ushort* __restrict__ outp) {
    __shared__ __align__(16) ushort smem[2][1360 * 8];  // 2 x 21.25 KB
    const int t = threadIdx.x;
    const int wid = t >> 6;
    const int lane = t & 63;
    const int lco = lane & 31, lhalf = lane >> 5;
    const int w0 = blockIdx.x * 32, h0 = blockIdx.y * 8, b = blockIdx.z;
    const ushort* ins[4] = {in0, in1, in2, in3};

    floatx16 acc0, acc1;
#pragma unroll
    for (int i = 0; i < 16; i++) { acc0[i] = 0.f; acc1[i] = 0.f; }

    auto stage = [&](const ushort* __restrict__ inp, ushort* sbuf) {
#pragma unroll
        for (int i = 0; i < 6; i++) {
            int u = (i * 4 + wid) * 64 + lane;
            if (u < 1360) {
                int row = u / 136;
                int rem = u - row * 136;
                int cb = rem / 34;
                int p = rem - cb * 34;
                int gh = h0 - 1 + row, gw = w0 - 1 + p;
                const ushort* src = ((unsigned)gh < 256u && (unsigned)gw < 256u)
                    ? (inp + (((size_t)b * HW_ + (size_t)gh * W_ + gw) * 32 + cb * 8))
                    : zp;
                __builtin_amdgcn_global_load_lds(
                    (const __attribute__((address_space(1))) unsigned int*)src,
                    (__attribute__((address_space(3))) unsigned int*)(sbuf + (i * 4 + wid) * 512),
                    16, 0, 0);
            }
        }
    };

    stage(ins[0], smem[0]);

    short8 bfrag[18];
#pragma unroll
    for (int ch = 0; ch < NCHUNK; ch++) {
        __syncthreads();  // drains vmcnt(0): staging for chunk ch complete (all waves)
        // issue bfrag loads FIRST (so later waits on them don't drain next stage)
        const ushort* wbp = wB + (((size_t)ch * 18 * 64 + lane)) * 8;
#pragma unroll
        for (int s = 0; s < 18; s++)
            bfrag[s] = *(const short8*)(wbp + s * 512);
        if (ch + 1 < NCHUNK) stage(ins[ch + 1], smem[(ch + 1) & 1]);

        const ushort* sb = smem[ch & 1];
#pragma unroll
        for (int s = 0; s < 18; s++) {
            const int khw = s >> 1;
            const int kh = khw / 3, kw = khw - kh * 3;
            const int cbr = ((s & 1) << 1) + lhalf;
            const int ww = lco + kw;
            const int r0 = wid * 2 + kh;
            short8 a0 = *(const short8*)(sb + (r0 * 136 + cbr * 34 + ww) * 8);
            short8 a1 = *(const short8*)(sb + ((r0 + 1) * 136 + cbr * 34 + ww) * 8);
            acc0 = __builtin_amdgcn_mfma_f32_32x32x16_bf16(a0, bfrag[s], acc0, 0, 0, 0);
            acc1 = __builtin_amdgcn_mfma_f32_32x32x16_bf16(a1, bfrag[s], acc1, 0, 0, 0);
        }
    }

    // epilogue: D col = co = lane&31; pixel row = (r&3) + 8*(r>>2) + 4*half
#pragma unroll
    for (int r = 0; r < 16; r++) {
        int prow = (r & 3) + 8 * (r >> 2) + 4 * lhalf;
        float v0 = acc0[r], v1 = acc1[r];
        if (RELU) { v0 = fmaxf(v0, 0.f); v1 = fmaxf(v1, 0.f); }
        ushort u0 = (lco < COOUT) ? f2bf(v0) : (ushort)0;
        ushort u1 = (lco < COOUT) ? f2bf(v1) : (ushort)0;
        size_t p0 = (((size_t)b * HW_ + (h0 + wid * 2) * W_ + w0 + prow) * 32) + lco;
        outp[p0] = u0;
        outp[p0 + (size_t)W_ * 32] = u1;
    }
}

// ============ attention head: 1x1 conv (16->4) + bias + sigmoid ============
__global__ __launch_bounds__(256) void att1x1(const ushort* __restrict__ a2,
                                              const float* __restrict__ w,
                                              const float* __restrict__ bias,
                                              ushort* __restrict__ wmap) {
    int idx = blockIdx.x * 256 + threadIdx.x;  // 8*HW
    float xin[16];
    {
        uint4 v0 = *(const uint4*)(a2 + (size_t)idx * 32);
        uint4 v1 = *(const uint4*)(a2 + (size_t)idx * 32 + 8);
        const ushort* u = (const ushort*)&v0;
#pragma unroll
        for (int j = 0; j < 8; j++) xin[j] = bf2f(u[j]);
        const ushort* u2 = (const ushort*)&v1;
#pragma unroll
        for (int j = 0; j < 8; j++) xin[8 + j] = bf2f(u2[j]);
    }
    ushort o[4];
#pragma unroll
    for (int g = 0; g < 4; g++) {
        float acc = bias[g];
#pragma unroll
        for (int ci = 0; ci < 16; ci++) acc = fmaf(xin[ci], w[g * 16 + ci], acc);
        o[g] = f2bf(sigmoidf_(acc));
    }
    *(uint2*)(wmap + (size_t)idx * 4) = *(const uint2*)o;
}

// ============ final 1x1 conv (32->1) + sigmoid, fp32 out ============
__global__ __launch_bounds__(256) void out1x1(const ushort* __restrict__ feat,
                                              const float* __restrict__ w,
                                              float* __restrict__ out) {
    int idx = blockIdx.x * 256 + threadIdx.x;
    float acc = 0.f;
    const ushort* f = feat + (size_t)idx * 32;
#pragma unroll
    for (int q = 0; q < 4; q++) {
        uint4 v = *(const uint4*)(f + q * 8);
        const ushort* u = (const ushort*)&v;
#pragma unroll
        for (int j = 0; j < 8; j++) acc = fmaf(bf2f(u[j]), w[q * 8 + j], acc);
    }
    out[idx] = sigmoidf_(acc);
}

// ============ fused fwd+bwd IRNN scan along one axis, gating fused ============
// VERT: scan h (tile = 4 w-columns). HORZ: scan w (tile = 4 h-rows).
// 128 threads: s = t>>5 in [0,4) picks column/row within tile, c = t&31 channel.
// Fwd streams feat from global (2-batch prefetch), echoes raw x into LDS;
// bwd replays from LDS (thread-private -> no barriers needed).
template<int VERT>
__global__ __launch_bounds__(128) void scan_pair(
    const ushort* __restrict__ feat, const float* __restrict__ alpha,
    const ushort* __restrict__ wmap, ushort* __restrict__ gfwd,
    ushort* __restrict__ gbwd, int gf, int gb) {
    __shared__ ushort echo[32768];  // 256 pos x 4 s x 32 c = 64 KB
    const int t = threadIdx.x;
    const int c = t & 31;
    const int s = t >> 5;
    const int tile = blockIdx.x;
    const int b = blockIdx.y;
    const float a = alpha[c];

    size_t xbase, wmbase, xstep, wmstep;
    if (VERT) {
        xbase  = ((size_t)b * HW_ + tile * 4 + s) * 32 + c;
        wmbase = ((size_t)b * HW_ + tile * 4 + s) * 4;
        xstep  = (size_t)W_ * 32;
        wmstep = (size_t)W_ * 4;
    } else {
        xbase  = ((size_t)b * HW_ + (size_t)(tile * 4 + s) * W_) * 32 + c;
        wmbase = ((size_t)b * HW_ + (size_t)(tile * 4 + s) * W_) * 4;
        xstep  = 32;
        wmstep = 4;
    }

    // ---------- forward ----------
    {
        ushort xr0[8], wr0[8], xr1[8], wr1[8];
        auto loadb = [&](int g, ushort* xd, ushort* wd) {
#pragma unroll
            for (int j = 0; j < 8; j++) {
                size_t pos = (size_t)(g * 8 + j);
                xd[j] = feat[xbase + pos * xstep];
                wd[j] = wmap[wmbase + pos * wmstep + gf];
            }
        };
        float prev = 0.f;
        auto compute8 = [&](int g, const ushort* xd, const ushort* wd) {
#pragma unroll
            for (int j = 0; j < 8; j++) {
                int pos = g * 8 + j;
                echo[(pos * 4 + s) * 32 + c] = xd[j];
                float cur = fmaxf(fmaf(a, prev, bf2f(xd[j])), 0.f);
                prev = cur;
                gfwd[xbase + (size_t)pos * xstep] = f2bf(cur * bf2f(wd[j]));
            }
        };
        loadb(0, xr0, wr0);
        loadb(1, xr1, wr1);
        for (int g = 0; g < 32; g += 2) {
            compute8(g, xr0, wr0);
            if (g + 2 < 32) loadb(g + 2, xr0, wr0);
            compute8(g + 1, xr1, wr1);
            if (g + 3 < 32) loadb(g + 3, xr1, wr1);
        }
    }

    // ---------- backward (x from LDS echo) ----------
    {
        ushort wr0[8], wr1[8];
        auto loadb = [&](int g, ushort* wd) {
#pragma unroll
            for (int j = 0; j < 8; j++) {
                int pos = 255 - (g * 8 + j);
                wd[j] = wmap[wmbase + (size_t)pos * wmstep + gb];
            }
        };
        float prev = 0.f;
        auto compute8 = [&](int g, const ushort* wd) {
#pragma unroll
            for (int j = 0; j < 8; j++) {
                int pos = 255 - (g * 8 + j);
                float xv = bf2f(echo[(pos * 4 + s) * 32 + c]);
                float cur = fmaxf(fmaf(a, prev, xv), 0.f);
                prev = cur;
                gbwd[xbase + (size_t)pos * xstep] = f2bf(cur * bf2f(wd[j]));
            }
        };
        loadb(0, wr0);
        loadb(1, wr1);
        for (int g = 0; g < 32; g += 2) {
            compute8(g, wr0);
            if (g + 2 < 32) loadb(g + 2, wr0);
            compute8(g + 1, wr1);
            if (g + 3 < 32) loadb(g + 3, wr1);
        }
    }
}

extern "C" void kernel_launch(void* const* d_in, const int* in_sizes, int n_in,
                              void* d_out, int out_size, void* d_ws, size_t ws_size,
                              hipStream_t stream) {
    const float* x      = (const float*)d_in[0];
    const float* alpha1 = (const float*)d_in[1];
    const float* alpha2 = (const float*)d_in[2];
    const float* w_in   = (const float*)d_in[3];
    const float* w2     = (const float*)d_in[4];
    const float* w3     = (const float*)d_in[5];
    const float* aw1    = (const float*)d_in[6];
    const float* aw2    = (const float*)d_in[7];
    const float* aw3    = (const float*)d_in[8];
    const float* ab3    = (const float*)d_in[9];
    const float* wout   = (const float*)d_in[10];
    float* out = (float*)d_out;

    // ---- workspace carve (ushorts), ~206 MB ----
    const size_t TEN = (size_t)8 * HW_ * 32;
    ushort* p = (ushort*)d_ws;
    ushort* xh    = p; p += TEN;
    ushort* feat  = p; p += TEN;
    ushort* g0    = p; p += TEN;
    ushort* g1    = p; p += TEN;
    ushort* g2    = p; p += TEN;
    ushort* g3    = p; p += TEN;
    ushort* wmap  = p; p += (size_t)8 * HW_ * 4;
    ushort* w_inB = p; p += 9216;
    ushort* w2B   = p; p += 36864;
    ushort* w3B   = p; p += 36864;
    ushort* aw1B  = p; p += 9216;
    ushort* aw2B  = p; p += 9216;
    ushort* zp    = p; p += 64;

    prep_weights<<<396, 256, 0, stream>>>(w_in, w2, w3, aw1, aw2,
                                          w_inB, w2B, w3B, aw1B, aw2B, zp);
    transform_x<<<dim3(4, 256, 8), 256, 0, stream>>>(x, xh);

    dim3 gconv(8, 32, 8);
    dim3 gscan(64, 8);
    // attention gate (a1/a2 overlay g0/g1)
    conv_mfma<1, 16, true><<<gconv, 256, 0, stream>>>(xh, xh, xh, xh, aw1B, zp, g0);
    conv_mfma<1, 16, true><<<gconv, 256, 0, stream>>>(g0, g0, g0, g0, aw2B, zp, g1);
    att1x1<<<2048, 256, 0, stream>>>(g1, aw3, ab3, wmap);

    // trunk
    conv_mfma<1, 32, false><<<gconv, 256, 0, stream>>>(xh, xh, xh, xh, w_inB, zp, feat);

    // round 1 scans: g0=td, g1=lr, g2=dt, g3=rl
    scan_pair<1><<<gscan, 128, 0, stream>>>(feat, alpha1, wmap, g0, g2, 0, 2);
    scan_pair<0><<<gscan, 128, 0, stream>>>(feat, alpha1, wmap, g1, g3, 1, 3);

    conv_mfma<4, 32, false><<<gconv, 256, 0, stream>>>(g0, g1, g2, g3, w2B, zp, feat);

    // round 2 scans
    scan_pair<1><<<gscan, 128, 0, stream>>>(feat, alpha2, wmap, g0, g2, 0, 2);
    scan_pair<0><<<gscan, 128, 0, stream>>>(feat, alpha2, wmap, g1, g3, 1, 3);

    conv_mfma<4, 32, true><<<gconv, 256, 0, stream>>>(g0, g1, g2, g3, w3B, zp, feat);

    out1x1<<<2048, 256, 0, stream>>>(feat, wout, out);
}